// Round 12
// baseline (1263.877 us; speedup 1.0000x reference)
//
#include <hip/hip_runtime.h>
#include <cstdint>
#include <cstddef>

#define HHEADS 16
#define DHEAD  64
#define NSEQ   2048
#define NBATCH 2
#define NDIM   1024
#define TOPKN  64
#define CAP    68
#define NROWS  (NBATCH*HHEADS*NSEQ)   // 65536

// ---------------------------------------------------------------------------
// Kernel 1: QKV GEMM.  x[4096,1024] @ Wqkv[1024,3072] + bqkv
// -> q,k,v each laid out [B,H,N,DH].  128x128 tile, 8x8 micro-tile, BK=32
// (half the barriers per FLOP vs BK=16).  Ascending-k chain -> bit-identical.
// ---------------------------------------------------------------------------
__global__ __launch_bounds__(256) void qkv_gemm(
    const float* __restrict__ x, const float* __restrict__ W,
    const float* __restrict__ bias,
    float* __restrict__ qout, float* __restrict__ kout, float* __restrict__ vout)
{
    __shared__ float As[32][128];   // transposed A tile, 16 KB
    __shared__ float Bs[32][128];   // 16 KB
    const int tid = threadIdx.x;
    const int rowBase = blockIdx.y * 128;
    const int colBase = blockIdx.x * 128;
    const int tx = tid & 15, ty = tid >> 4;
    const int arow = tid & 127, ag = (tid >> 7) << 4;   // A: row, k-half {0,16}
    const int bkk = tid >> 5,  bc4 = tid & 31;          // B: k-row 0..7, col f4

    float acc[8][8] = {};
    float4 ap[4], bp[4];
    const float* xrow = &x[(size_t)(rowBase + arow) * NDIM];
#pragma unroll
    for (int j = 0; j < 4; j++)
        ap[j] = *reinterpret_cast<const float4*>(xrow + ag + j * 4);
#pragma unroll
    for (int i = 0; i < 4; i++)
        bp[i] = *reinterpret_cast<const float4*>(&W[(size_t)(bkk + 8 * i) * 3072 + colBase + bc4 * 4]);

    for (int k0 = 0; k0 < NDIM; k0 += 32) {
        __syncthreads();   // previous tile's compute done
#pragma unroll
        for (int j = 0; j < 4; j++) {
            As[ag + j * 4 + 0][arow] = ap[j].x;
            As[ag + j * 4 + 1][arow] = ap[j].y;
            As[ag + j * 4 + 2][arow] = ap[j].z;
            As[ag + j * 4 + 3][arow] = ap[j].w;
        }
#pragma unroll
        for (int i = 0; i < 4; i++)
            *reinterpret_cast<float4*>(&Bs[bkk + 8 * i][bc4 * 4]) = bp[i];
        __syncthreads();   // staged
        if (k0 + 32 < NDIM) {   // prefetch next tile; latency hidden by compute
#pragma unroll
            for (int j = 0; j < 4; j++)
                ap[j] = *reinterpret_cast<const float4*>(xrow + k0 + 32 + ag + j * 4);
#pragma unroll
            for (int i = 0; i < 4; i++)
                bp[i] = *reinterpret_cast<const float4*>(&W[(size_t)(k0 + 32 + bkk + 8 * i) * 3072 + colBase + bc4 * 4]);
        }
#pragma unroll
        for (int kk = 0; kk < 32; kk++) {
            float4 alo = *reinterpret_cast<const float4*>(&As[kk][ty * 4]);
            float4 ahi = *reinterpret_cast<const float4*>(&As[kk][64 + ty * 4]);
            float4 blo = *reinterpret_cast<const float4*>(&Bs[kk][tx * 4]);
            float4 bhi = *reinterpret_cast<const float4*>(&Bs[kk][64 + tx * 4]);
            float ar[8] = {alo.x, alo.y, alo.z, alo.w, ahi.x, ahi.y, ahi.z, ahi.w};
            float br[8] = {blo.x, blo.y, blo.z, blo.w, bhi.x, bhi.y, bhi.z, bhi.w};
#pragma unroll
            for (int i = 0; i < 8; i++)
#pragma unroll
                for (int j = 0; j < 8; j++) acc[i][j] += ar[i] * br[j];
        }
    }

    const int which = colBase >> 10;
    float* dst = which == 0 ? qout : (which == 1 ? kout : vout);
#pragma unroll
    for (int jh = 0; jh < 2; jh++) {
        const int colh = colBase + jh * 64 + tx * 4;
        const int h = (colh & 1023) >> 6;
        const int d0 = colh & 63;
        float4 bb = *reinterpret_cast<const float4*>(&bias[colh]);
#pragma unroll
        for (int ih = 0; ih < 2; ih++)
#pragma unroll
            for (int i = 0; i < 4; i++) {
                int r = rowBase + ih * 64 + ty * 4 + i;
                int b = r >> 11, n = r & 2047;
                size_t o = ((size_t)((b << 4) + h) * NSEQ + n) * DHEAD + d0;
                float4 st;
                st.x = acc[ih * 4 + i][jh * 4 + 0] + bb.x;
                st.y = acc[ih * 4 + i][jh * 4 + 1] + bb.y;
                st.z = acc[ih * 4 + i][jh * 4 + 2] + bb.z;
                st.w = acc[ih * 4 + i][jh * 4 + 3] + bb.w;
                *reinterpret_cast<float4*>(&dst[o]) = st;
            }
    }
}

// ---------------------------------------------------------------------------
// order-preserving float<->uint key transforms
// ---------------------------------------------------------------------------
__device__ __forceinline__ uint32_t f2key(float f) {
    uint32_t u = __float_as_uint(f);
    return (u & 0x80000000u) ? ~u : (u | 0x80000000u);
}
__device__ __forceinline__ float key2f(uint32_t k) {
    uint32_t u = (k & 0x80000000u) ? (k & 0x7FFFFFFFu) : ~k;
    return __uint_as_float(u);
}

// Per-row top-64 + softmax + compacted emit, entirely from 32 key registers.
// k[t] holds key of score j = (t>>2)*256 + lane*4 + (t&3).
__device__ __forceinline__ void topk_emit(
    uint32_t (&k)[32], float m, int row, int lane,
    int* __restrict__ tki, float* __restrict__ tkp, int* __restrict__ tkc)
{
    // bisection for the 64th-largest key (ballot count, wave-uniform scalar)
    uint32_t lo = 0u, hi = 0xFFFFFFFFu;
    while (lo < hi) {
        uint32_t mid = (uint32_t)(((uint64_t)lo + (uint64_t)hi + 1ull) >> 1);
        int c = 0;
#pragma unroll
        for (int t = 0; t < 32; t++)
            c += (int)__popcll(__ballot(k[t] >= mid));
        if (c >= TOPKN) { lo = mid; if (c == TOPKN) { hi = mid; } }
        else hi = mid - 1;
    }
    const uint32_t thr = lo;

    // softmax over kept entries (overwrite k[t] with exp bits; keep mask)
    uint32_t keep = 0;
    float sum = 0.f;
#pragma unroll
    for (int t = 0; t < 32; t++) {
        bool kp = (k[t] >= thr);
        float e = kp ? __expf(key2f(k[t]) - m) : 0.f;
        k[t] = __float_as_uint(e);
        sum += e;
        keep |= kp ? (1u << t) : 0u;
    }
#pragma unroll
    for (int off = 32; off >= 1; off >>= 1) sum += __shfl_xor(sum, off);
    const float rs = 1.f / sum;

    // compacted emit
    int base = 0;
    const unsigned long long below = (1ull << lane) - 1ull;
#pragma unroll
    for (int t = 0; t < 32; t++) {
        bool kp = (keep >> t) & 1u;
        unsigned long long mask = __ballot(kp);
        if (kp) {
            int pos = base + (int)__popcll(mask & below);
            if (pos < CAP) {
                tki[(size_t)row * CAP + pos] = ((t >> 2) << 8) + (lane << 2) + (t & 3);
                tkp[(size_t)row * CAP + pos] = __uint_as_float(k[t]) * rs;
            }
        }
        base += (int)__popcll(mask);
    }
    if (lane == 0) tkc[row] = base < CAP ? base : CAP;
}

// direct global->LDS 16B copy (no VGPR round-trip). lds base must be
// wave-uniform; HW scatters lane i to base + i*16 (m104/m108).
__device__ __forceinline__ void gload_lds16(const void* g, void* l) {
    __builtin_amdgcn_global_load_lds(
        (const __attribute__((address_space(1))) unsigned int*)g,
        (__attribute__((address_space(3))) unsigned int*)l,
        16, 0, 0);
}

// ---------------------------------------------------------------------------
// Kernel 2a: scores as a GEMM.  Per (b,h): S = Q[2048x64] @ K^T[64x2048].
// Tile 128(q) x 64(key), K-depth = 64 = ONE stage, ONE barrier, no k-loop.
// Micro-tile 8x4: per kk, 3 ds_read_b128 feed 32 FMAs.  Keys f2key(s*0.125)
// stream to chunked keyg.  d-accumulation single ascending chain.
// ---------------------------------------------------------------------------
__global__ __launch_bounds__(256) void scores_gemm(
    const float* __restrict__ qg, const float* __restrict__ kg,
    uint32_t* __restrict__ keyg, int n0, int Nc)
{
    __shared__ float Qs[64][128];   // [d][qrow]  32 KB
    __shared__ float Kb[64][64];    // [d][key]   16 KB
    const int tid = threadIdx.x;
    const int bh = blockIdx.z;
    const int rowBase = n0 + blockIdx.y * 128;   // global n of tile row 0
    const int colBase = blockIdx.x * 64;         // key index of tile col 0
    const int tx = tid & 15, ty = tid >> 4;      // ty 0..15

    // stage Q tile transposed (thread: row = tid&127, 8 float4s along d)
    {
        const int arow = tid & 127, g = tid >> 7;   // g in {0,1}
        const float* qrow = &qg[((size_t)bh * NSEQ + rowBase + arow) * DHEAD];
#pragma unroll
        for (int j = 0; j < 8; j++) {
            int f = g * 8 + j;
            float4 v = *reinterpret_cast<const float4*>(qrow + f * 4);
            Qs[f * 4 + 0][arow] = v.x; Qs[f * 4 + 1][arow] = v.y;
            Qs[f * 4 + 2][arow] = v.z; Qs[f * 4 + 3][arow] = v.w;
        }
    }
    // stage K tile transposed (thread: key = tid&63, 4 float4s along d)
    {
        const int j = tid & 63, g = tid >> 6;       // g in 0..3
        const float* krow = &kg[((size_t)bh * NSEQ + colBase + j) * DHEAD];
#pragma unroll
        for (int i = 0; i < 4; i++) {
            int f = g * 4 + i;
            float4 v = *reinterpret_cast<const float4*>(krow + f * 4);
            Kb[f * 4 + 0][j] = v.x; Kb[f * 4 + 1][j] = v.y;
            Kb[f * 4 + 2][j] = v.z; Kb[f * 4 + 3][j] = v.w;
        }
    }
    __syncthreads();

    float acc[8][4] = {};
#pragma unroll
    for (int kk = 0; kk < 64; kk++) {
        float4 q0 = *reinterpret_cast<const float4*>(&Qs[kk][ty * 8]);
        float4 q1 = *reinterpret_cast<const float4*>(&Qs[kk][ty * 8 + 4]);
        float4 kv = *reinterpret_cast<const float4*>(&Kb[kk][tx * 4]);
        float qr[8] = {q0.x, q0.y, q0.z, q0.w, q1.x, q1.y, q1.z, q1.w};
        float kr[4] = {kv.x, kv.y, kv.z, kv.w};
#pragma unroll
        for (int r = 0; r < 8; r++)
#pragma unroll
            for (int c = 0; c < 4; c++) acc[r][c] += qr[r] * kr[c];
    }

    // encode + store keys (per row: one uint4, wave stores 256B contiguous)
    const size_t rloc0 = (size_t)bh * Nc + (blockIdx.y * 128 + ty * 8);
#pragma unroll
    for (int r = 0; r < 8; r++) {
        uint4 kv4;
        kv4.x = f2key(acc[r][0] * 0.125f);
        kv4.y = f2key(acc[r][1] * 0.125f);
        kv4.z = f2key(acc[r][2] * 0.125f);
        kv4.w = f2key(acc[r][3] * 0.125f);
        *reinterpret_cast<uint4*>(&keyg[(rloc0 + r) * 2048 + colBase + tx * 4]) = kv4;
    }
}

// ---------------------------------------------------------------------------
// Kernel 2b: top-k + softmax from keyg chunk.  1 wave per row, no LDS ->
// high occupancy hides the bisection's serial chain and the key reload.
// ---------------------------------------------------------------------------
__global__ __launch_bounds__(256) void topk_kernel(
    const uint32_t* __restrict__ keyg,
    int* __restrict__ tki, float* __restrict__ tkp, int* __restrict__ tkc,
    int n0, int lgNc)
{
    const int rloc = blockIdx.x * 4 + (threadIdx.x >> 6);
    const int lane = threadIdx.x & 63;
    const int bh = rloc >> lgNc;
    const int n  = n0 + (rloc & ((1 << lgNc) - 1));
    const int row = (bh << 11) + n;
    const uint4* src = reinterpret_cast<const uint4*>(keyg + (size_t)rloc * 2048);

    uint32_t k[32];
#pragma unroll
    for (int p = 0; p < 8; p++) {
        uint4 c4 = src[p * 64 + lane];
        k[p * 4 + 0] = c4.x; k[p * 4 + 1] = c4.y;
        k[p * 4 + 2] = c4.z; k[p * 4 + 3] = c4.w;
    }
    uint32_t km = 0;
#pragma unroll
    for (int t = 0; t < 32; t++) km = k[t] > km ? k[t] : km;
#pragma unroll
    for (int off = 32; off >= 1; off >>= 1) {
        uint32_t o = __shfl_xor(km, off);
        km = o > km ? o : km;
    }
    topk_emit(k, key2f(km), row, lane, tki, tkp, tkc);
}

// ---------------------------------------------------------------------------
// Kernel 2 (fallback, fused via LDS key bounce; R4 design).  Unreachable
// given ws_size >= 210 MB (R10 evidence), kept for safety.
// ---------------------------------------------------------------------------
__global__ __launch_bounds__(256) void scores_topk(
    const float* __restrict__ qg, const float* __restrict__ kg,
    int* __restrict__ tki, float* __restrict__ tkp, int* __restrict__ tkc)
{
    __shared__ float4   Ks[2][2048];
    __shared__ float    qs[8][64];
    __shared__ uint32_t keyk[8][2048];
    const int bh = blockIdx.y;
    const int wave = threadIdx.x >> 6, lane = threadIdx.x & 63;
    const size_t kbase = (size_t)bh * NSEQ * DHEAD;

    if (threadIdx.x < 128) {
        int r = threadIdx.x >> 4, c4 = threadIdx.x & 15;
        *reinterpret_cast<float4*>(&qs[r][c4 << 2]) =
            *reinterpret_cast<const float4*>(
                &qg[((size_t)bh * NSEQ + blockIdx.x * 8 + r) * DHEAD + (c4 << 2)]);
    }

    const int jw  = wave * 4 + (lane >> 4);
    const int swz = lane & 15;
    auto stage = [&](int T, int buf) {
#pragma unroll
        for (int rep = 0; rep < 8; rep++) {
            int j = rep * 16 + jw;
            int c = swz ^ (j & 7);
            gload_lds16(&kg[kbase + (size_t)(T * 128 + j) * DHEAD + (c << 2)],
                        (char*)&Ks[buf][0] + (rep * 4096 + wave * 1024));
        }
    };

    stage(0, 0);
    __syncthreads();

    const int rA = wave * 2, rB = rA + 1;
    float mA = -3.4e38f, mB = -3.4e38f;

    for (int KT = 0; KT < 16; KT++) {
        const int cur = KT & 1;
        if (KT < 15) stage(KT + 1, cur ^ 1);

        float sA0 = 0.f, sA1 = 0.f, sB0 = 0.f, sB1 = 0.f;
#pragma unroll
        for (int c = 0; c < 16; c++) {
            float4 qa = *reinterpret_cast<const float4*>(&qs[rA][c << 2]);
            float4 qb = *reinterpret_cast<const float4*>(&qs[rB][c << 2]);
            int j0 = lane, j1 = 64 + lane;
            float4 kv0 = Ks[cur][(j0 << 4) + (c ^ (j0 & 7))];
            float4 kv1 = Ks[cur][(j1 << 4) + (c ^ (j1 & 7))];
            sA0 += qa.x * kv0.x + qa.y * kv0.y + qa.z * kv0.z + qa.w * kv0.w;
            sA1 += qa.x * kv1.x + qa.y * kv1.y + qa.z * kv1.z + qa.w * kv1.w;
            sB0 += qb.x * kv0.x + qb.y * kv0.y + qb.z * kv0.z + qb.w * kv0.w;
            sB1 += qb.x * kv1.x + qb.y * kv1.y + qb.z * kv1.z + qb.w * kv1.w;
        }
        sA0 *= 0.125f; sA1 *= 0.125f; sB0 *= 0.125f; sB1 *= 0.125f;
        mA = fmaxf(mA, fmaxf(sA0, sA1));
        mB = fmaxf(mB, fmaxf(sB0, sB1));
        keyk[rA][KT * 128 + lane]      = f2key(sA0);
        keyk[rA][KT * 128 + 64 + lane] = f2key(sA1);
        keyk[rB][KT * 128 + lane]      = f2key(sB0);
        keyk[rB][KT * 128 + 64 + lane] = f2key(sB1);
        __syncthreads();
    }

#pragma unroll
    for (int off = 32; off >= 1; off >>= 1) {
        mA = fmaxf(mA, __shfl_xor(mA, off));
        mB = fmaxf(mB, __shfl_xor(mB, off));
    }

    const int rowA = bh * NSEQ + blockIdx.x * 8 + wave * 2;
    {
        const uint4* src = reinterpret_cast<const uint4*>(&keyk[rA][0]);
        uint32_t k[32];
#pragma unroll
        for (int p = 0; p < 8; p++) {
            uint4 c4 = src[p * 64 + lane];
            k[p * 4 + 0] = c4.x; k[p * 4 + 1] = c4.y;
            k[p * 4 + 2] = c4.z; k[p * 4 + 3] = c4.w;
        }
        topk_emit(k, mA, rowA, lane, tki, tkp, tkc);
    }
    {
        const uint4* src = reinterpret_cast<const uint4*>(&keyk[rB][0]);
        uint32_t k[32];
#pragma unroll
        for (int p = 0; p < 8; p++) {
            uint4 c4 = src[p * 64 + lane];
            k[p * 4 + 0] = c4.x; k[p * 4 + 1] = c4.y;
            k[p * 4 + 2] = c4.z; k[p * 4 + 3] = c4.w;
        }
        topk_emit(k, mB, rowA + 1, lane, tki, tkp, tkc);
    }
}

// ---------------------------------------------------------------------------
// Kernel 3: one propagation step.  v_out[n] = sum_j p[n,j] * v_in[idx[n,j]];
// res(+)= sigmoid(alphas_raw[iter,h]) * v_out, res in [B,N,H*DH] layout.
// idx/prob loads vectorized (CAP=68 -> 272B row stride, 16B-aligned).
// ---------------------------------------------------------------------------
__global__ __launch_bounds__(256) void prop(
    const float* __restrict__ vin, float* __restrict__ vout,
    float* __restrict__ res, const float* __restrict__ araw,
    const int* __restrict__ tki, const float* __restrict__ tkp,
    const int* __restrict__ tkc, int iter)
{
    const int row = blockIdx.x * 4 + (threadIdx.x >> 6);
    const int lane = threadIdx.x & 63;
    const int bh = row >> 11;
    const int h = bh & 15;
    const int cnt = tkc[row];
    const int* idx = tki + (size_t)row * CAP;
    const float* pr = tkp + (size_t)row * CAP;
    const float* vb = vin + (size_t)bh * NSEQ * DHEAD;

    float a0 = 0.f, a1 = 0.f, a2 = 0.f, a3 = 0.f;
    int j = 0;
    for (; j + 4 <= cnt; j += 4) {
        int4   i4 = *reinterpret_cast<const int4*>(&idx[j]);
        float4 p4 = *reinterpret_cast<const float4*>(&pr[j]);
        a0 += p4.x * vb[(size_t)i4.x * DHEAD + lane];
        a1 += p4.y * vb[(size_t)i4.y * DHEAD + lane];
        a2 += p4.z * vb[(size_t)i4.z * DHEAD + lane];
        a3 += p4.w * vb[(size_t)i4.w * DHEAD + lane];
    }
    for (; j < cnt; j++) a0 += pr[j] * vb[(size_t)idx[j] * DHEAD + lane];
    float acc = (a0 + a1) + (a2 + a3);

    vout[(size_t)row * DHEAD + lane] = acc;

    float ar = araw[iter * HHEADS + h];
    float alpha = 1.f / (1.f + __expf(-ar));
    const int b = row >> 15, n = row & 2047;
    size_t ro = ((size_t)(b * NSEQ + n)) * 1024 + h * DHEAD + lane;
    if (iter == 1) res[ro] = alpha * acc;
    else           res[ro] += alpha * acc;
}

// ---------------------------------------------------------------------------
// Kernel 4: output GEMM.  res[4096,1024] @ Wout[1024,1024] + bout -> out
// 128x64 tile, 8x4 micro-tile, BK=32 (512 blocks -> 2/CU).
// Ascending-k chain -> bit-identical to the 64x64 version.
// ---------------------------------------------------------------------------
__global__ __launch_bounds__(256) void out_gemm(
    const float* __restrict__ A, const float* __restrict__ W,
    const float* __restrict__ bias, float* __restrict__ out)
{
    __shared__ float As[32][128];   // 16 KB
    __shared__ float Bs[32][64];    // 8 KB
    const int tid = threadIdx.x;
    const int rowBase = blockIdx.y * 128;
    const int colBase = blockIdx.x * 64;
    const int tx = tid & 15, ty = tid >> 4;
    const int arow = tid & 127, ag = (tid >> 7) << 4;   // A: row, k-half {0,16}
    const int bkk = tid >> 4,  bc4 = tid & 15;          // B: k-row 0..15, col f4

    float acc[8][4] = {};
    float4 ap[4], bp[2];
    const float* Arow = &A[(size_t)(rowBase + arow) * 1024];
#pragma unroll
    for (int j = 0; j < 4; j++)
        ap[j] = *reinterpret_cast<const float4*>(Arow + ag + j * 4);
#pragma unroll
    for (int i = 0; i < 2; i++)
        bp[i] = *reinterpret_cast<const float4*>(&W[(size_t)(bkk + 16 * i) * 1024 + colBase + bc4 * 4]);

    for (int k0 = 0; k0 < 1024; k0 += 32) {
        __syncthreads();
#pragma unroll
        for (int j = 0; j < 4; j++) {
            As[ag + j * 4 + 0][arow] = ap[j].x;
            As[ag + j * 4 + 1][arow] = ap[j].y;
            As[ag + j * 4 + 2][arow] = ap[j].z;
            As[ag + j * 4 + 3][arow] = ap[j].w;
        }
#pragma unroll
        for (int i = 0; i < 2; i++)
            *reinterpret_cast<float4*>(&Bs[bkk + 16 * i][bc4 * 4]) = bp[i];
        __syncthreads();
        if (k0 + 32 < 1024) {
#pragma unroll
            for (int j = 0; j < 4; j++)
                ap[j] = *reinterpret_cast<const float4*>(Arow + k0 + 32 + ag + j * 4);
#pragma unroll
            for (int i = 0; i < 2; i++)
                bp[i] = *reinterpret_cast<const float4*>(&W[(size_t)(k0 + 32 + bkk + 16 * i) * 1024 + colBase + bc4 * 4]);
        }
#pragma unroll
        for (int kk = 0; kk < 32; kk++) {
            float4 a0 = *reinterpret_cast<const float4*>(&As[kk][ty * 8]);
            float4 a1 = *reinterpret_cast<const float4*>(&As[kk][ty * 8 + 4]);
            float4 bv = *reinterpret_cast<const float4*>(&Bs[kk][tx * 4]);
            float qr[8] = {a0.x, a0.y, a0.z, a0.w, a1.x, a1.y, a1.z, a1.w};
            float br[4] = {bv.x, bv.y, bv.z, bv.w};
#pragma unroll
            for (int r = 0; r < 8; r++)
#pragma unroll
                for (int c = 0; c < 4; c++) acc[r][c] += qr[r] * br[c];
        }
    }

    float4 bb = *reinterpret_cast<const float4*>(&bias[colBase + tx * 4]);
#pragma unroll
    for (int r = 0; r < 8; r++) {
        int row = rowBase + ty * 8 + r;
        float4 st;
        st.x = acc[r][0] + bb.x; st.y = acc[r][1] + bb.y;
        st.z = acc[r][2] + bb.z; st.w = acc[r][3] + bb.w;
        *reinterpret_cast<float4*>(&out[(size_t)row * 1024 + colBase + tx * 4]) = st;
    }
}

// ---------------------------------------------------------------------------
extern "C" void kernel_launch(void* const* d_in, const int* in_sizes, int n_in,
                              void* d_out, int out_size, void* d_ws, size_t ws_size,
                              hipStream_t stream)
{
    const float* x    = (const float*)d_in[0];
    const float* Wqkv = (const float*)d_in[1];
    const float* bqkv = (const float*)d_in[2];
    const float* Wout = (const float*)d_in[3];
    const float* bout = (const float*)d_in[4];
    const float* araw = (const float*)d_in[5];
    float* out = (float*)d_out;

    const size_t SEG = (size_t)1 << 22;   // 4M floats = one [B,H,N,DH] tensor
    float* ws = (float*)d_ws;
    float* q   = ws;                // [0, 16MB)
    float* k   = q + SEG;           // [16, 32MB)
    float* v   = k + SEG;           // [32, 48MB)
    int*   tki = (int*)(v + SEG);                   // 65536*68 ints (17.8MB)
    float* tkp = (float*)(tki + (size_t)NROWS * CAP);
    int*   tkc = (int*)(tkp + (size_t)NROWS * CAP);
    uint32_t* keyg = (uint32_t*)(tkc + NROWS);      // chunked key scratch
    float* vA  = (float*)keyg;      // keyg dead before prop1; alias (16MB)
    float* res = q;                 // q dead after scores; alias

    const size_t keyg_off = (size_t)((char*)keyg - (char*)d_ws);
    const size_t leftover = ws_size > keyg_off ? ws_size - keyg_off : 0;

    // largest power-of-two Nc (query positions per chunk) whose keyg fits:
    // bytes(Nc) = 32 slices * Nc rows * 2048 keys * 4B = Nc << 18
    int Nc = NSEQ;
    while (Nc >= 128 && (((size_t)Nc) << 18) > leftover) Nc >>= 1;

    qkv_gemm<<<dim3(24, 32), 256, 0, stream>>>(x, Wqkv, bqkv, q, k, v);

    if (Nc >= 128) {
        int lgNc = __builtin_ctz((unsigned)Nc);
        for (int n0 = 0; n0 < NSEQ; n0 += Nc) {
            scores_gemm<<<dim3(32, Nc / 128, 32), 256, 0, stream>>>(q, k, keyg, n0, Nc);
            topk_kernel<<<dim3(32 * Nc / 4), 256, 0, stream>>>(keyg, tki, tkp, tkc, n0, lgNc);
        }
    } else {
        scores_topk<<<dim3(256, 32), 256, 0, stream>>>(q, k, tki, tkp, tkc);
    }

    prop<<<dim3(NROWS / 4), 256, 0, stream>>>(v,  vA, res, araw, tki, tkp, tkc, 1);
    prop<<<dim3(NROWS / 4), 256, 0, stream>>>(vA, v,  res, araw, tki, tkp, tkc, 2);
    prop<<<dim3(NROWS / 4), 256, 0, stream>>>(v,  vA, res, araw, tki, tkp, tkc, 3);
    out_gemm<<<dim3(16, 32), 256, 0, stream>>>(res, Wout, bout, out);
}

// Round 13
// 1225.542 us; speedup vs baseline: 1.0313x; 1.0313x over previous
//
#include <hip/hip_runtime.h>
#include <cstdint>
#include <cstddef>

#define HHEADS 16
#define DHEAD  64
#define NSEQ   2048
#define NBATCH 2
#define NDIM   1024
#define TOPKN  64
#define CAP    68
#define NROWS  (NBATCH*HHEADS*NSEQ)   // 65536

// ---------------------------------------------------------------------------
// Kernel 1: QKV GEMM.  x[4096,1024] @ Wqkv[1024,3072] + bqkv
// -> q,k,v each laid out [B,H,N,DH].  128x128 tile, 8x8 micro-tile, BK=16
// (R8-proven: 312 us, VALUBusy 69%, 0 bank conflicts; BK=32 regressed).
// ---------------------------------------------------------------------------
__global__ __launch_bounds__(256) void qkv_gemm(
    const float* __restrict__ x, const float* __restrict__ W,
    const float* __restrict__ bias,
    float* __restrict__ qout, float* __restrict__ kout, float* __restrict__ vout)
{
    __shared__ float As[16][128];   // transposed A tile
    __shared__ float Bs[16][128];
    const int tid = threadIdx.x;
    const int rowBase = blockIdx.y * 128;
    const int colBase = blockIdx.x * 128;
    const int tx = tid & 15, ty = tid >> 4;
    const int arow = tid & 127, akq = tid >> 7;     // A: row, k-quarter (0/1)
    const int bkk = tid >> 5,  bc4 = tid & 31;      // B: kk row, col float4

    float acc[8][8] = {};
    float4 a0 = *reinterpret_cast<const float4*>(&x[(size_t)(rowBase + arow) * NDIM + akq * 4]);
    float4 a1 = *reinterpret_cast<const float4*>(&x[(size_t)(rowBase + arow) * NDIM + (akq + 2) * 4]);
    float4 b0 = *reinterpret_cast<const float4*>(&W[(size_t)bkk * 3072 + colBase + bc4 * 4]);
    float4 b1 = *reinterpret_cast<const float4*>(&W[(size_t)(bkk + 8) * 3072 + colBase + bc4 * 4]);

    for (int k0 = 0; k0 < NDIM; k0 += 16) {
        __syncthreads();   // previous tile's compute done
        As[akq * 4 + 0][arow] = a0.x; As[akq * 4 + 1][arow] = a0.y;
        As[akq * 4 + 2][arow] = a0.z; As[akq * 4 + 3][arow] = a0.w;
        As[(akq + 2) * 4 + 0][arow] = a1.x; As[(akq + 2) * 4 + 1][arow] = a1.y;
        As[(akq + 2) * 4 + 2][arow] = a1.z; As[(akq + 2) * 4 + 3][arow] = a1.w;
        *reinterpret_cast<float4*>(&Bs[bkk][bc4 * 4])     = b0;
        *reinterpret_cast<float4*>(&Bs[bkk + 8][bc4 * 4]) = b1;
        __syncthreads();   // staged
        if (k0 + 16 < NDIM) {   // prefetch next tile; latency hidden by compute
            a0 = *reinterpret_cast<const float4*>(&x[(size_t)(rowBase + arow) * NDIM + k0 + 16 + akq * 4]);
            a1 = *reinterpret_cast<const float4*>(&x[(size_t)(rowBase + arow) * NDIM + k0 + 16 + (akq + 2) * 4]);
            b0 = *reinterpret_cast<const float4*>(&W[(size_t)(k0 + 16 + bkk) * 3072 + colBase + bc4 * 4]);
            b1 = *reinterpret_cast<const float4*>(&W[(size_t)(k0 + 16 + bkk + 8) * 3072 + colBase + bc4 * 4]);
        }
#pragma unroll
        for (int kk = 0; kk < 16; kk++) {
            float4 alo = *reinterpret_cast<const float4*>(&As[kk][ty * 4]);
            float4 ahi = *reinterpret_cast<const float4*>(&As[kk][64 + ty * 4]);
            float4 blo = *reinterpret_cast<const float4*>(&Bs[kk][tx * 4]);
            float4 bhi = *reinterpret_cast<const float4*>(&Bs[kk][64 + tx * 4]);
            float ar[8] = {alo.x, alo.y, alo.z, alo.w, ahi.x, ahi.y, ahi.z, ahi.w};
            float br[8] = {blo.x, blo.y, blo.z, blo.w, bhi.x, bhi.y, bhi.z, bhi.w};
#pragma unroll
            for (int i = 0; i < 8; i++)
#pragma unroll
                for (int j = 0; j < 8; j++) acc[i][j] += ar[i] * br[j];
        }
    }

    const int which = colBase >> 10;
    float* dst = which == 0 ? qout : (which == 1 ? kout : vout);
#pragma unroll
    for (int jh = 0; jh < 2; jh++) {
        const int colh = colBase + jh * 64 + tx * 4;
        const int h = (colh & 1023) >> 6;
        const int d0 = colh & 63;
        float4 bb = *reinterpret_cast<const float4*>(&bias[colh]);
#pragma unroll
        for (int ih = 0; ih < 2; ih++)
#pragma unroll
            for (int i = 0; i < 4; i++) {
                int r = rowBase + ih * 64 + ty * 4 + i;
                int b = r >> 11, n = r & 2047;
                size_t o = ((size_t)((b << 4) + h) * NSEQ + n) * DHEAD + d0;
                float4 st;
                st.x = acc[ih * 4 + i][jh * 4 + 0] + bb.x;
                st.y = acc[ih * 4 + i][jh * 4 + 1] + bb.y;
                st.z = acc[ih * 4 + i][jh * 4 + 2] + bb.z;
                st.w = acc[ih * 4 + i][jh * 4 + 3] + bb.w;
                *reinterpret_cast<float4*>(&dst[o]) = st;
            }
    }
}

// ---------------------------------------------------------------------------
// order-preserving float<->uint key transforms
// ---------------------------------------------------------------------------
__device__ __forceinline__ uint32_t f2key(float f) {
    uint32_t u = __float_as_uint(f);
    return (u & 0x80000000u) ? ~u : (u | 0x80000000u);
}
__device__ __forceinline__ float key2f(uint32_t k) {
    uint32_t u = (k & 0x80000000u) ? (k & 0x7FFFFFFFu) : ~k;
    return __uint_as_float(u);
}

// Per-row top-64 + softmax + compacted emit, entirely from 32 key registers.
// k[t] holds key of score j = (t>>2)*256 + lane*4 + (t&3).
__device__ __forceinline__ void topk_emit(
    uint32_t (&k)[32], float m, int row, int lane,
    int* __restrict__ tki, float* __restrict__ tkp, int* __restrict__ tkc)
{
    // bisection for the 64th-largest key (ballot count, wave-uniform scalar)
    uint32_t lo = 0u, hi = 0xFFFFFFFFu;
    while (lo < hi) {
        uint32_t mid = (uint32_t)(((uint64_t)lo + (uint64_t)hi + 1ull) >> 1);
        int c = 0;
#pragma unroll
        for (int t = 0; t < 32; t++)
            c += (int)__popcll(__ballot(k[t] >= mid));
        if (c >= TOPKN) { lo = mid; if (c == TOPKN) { hi = mid; } }
        else hi = mid - 1;
    }
    const uint32_t thr = lo;

    // softmax over kept entries (overwrite k[t] with exp bits; keep mask)
    uint32_t keep = 0;
    float sum = 0.f;
#pragma unroll
    for (int t = 0; t < 32; t++) {
        bool kp = (k[t] >= thr);
        float e = kp ? __expf(key2f(k[t]) - m) : 0.f;
        k[t] = __float_as_uint(e);
        sum += e;
        keep |= kp ? (1u << t) : 0u;
    }
#pragma unroll
    for (int off = 32; off >= 1; off >>= 1) sum += __shfl_xor(sum, off);
    const float rs = 1.f / sum;

    // compacted emit
    int base = 0;
    const unsigned long long below = (1ull << lane) - 1ull;
#pragma unroll
    for (int t = 0; t < 32; t++) {
        bool kp = (keep >> t) & 1u;
        unsigned long long mask = __ballot(kp);
        if (kp) {
            int pos = base + (int)__popcll(mask & below);
            if (pos < CAP) {
                tki[(size_t)row * CAP + pos] = ((t >> 2) << 8) + (lane << 2) + (t & 3);
                tkp[(size_t)row * CAP + pos] = __uint_as_float(k[t]) * rs;
            }
        }
        base += (int)__popcll(mask);
    }
    if (lane == 0) tkc[row] = base < CAP ? base : CAP;
}

// direct global->LDS 16B copy (no VGPR round-trip). lds base must be
// wave-uniform; HW scatters lane i to base + i*16 (m104/m108).
__device__ __forceinline__ void gload_lds16(const void* g, void* l) {
    __builtin_amdgcn_global_load_lds(
        (const __attribute__((address_space(1))) unsigned int*)g,
        (__attribute__((address_space(3))) unsigned int*)l,
        16, 0, 0);
}

// ---------------------------------------------------------------------------
// Kernel 2a: scores as a GEMM.  Per (b,h): S = Q[2048x64] @ K^T[64x2048].
// Tile 128(q) x 64(key), K-depth = 64 = ONE stage, ONE barrier, no k-loop.
// Micro-tile 8x4: per kk, 3 ds_read_b128 feed 32 FMAs.  Keys f2key(s*0.125)
// stream to chunked keyg.  d-accumulation single ascending chain.
// ---------------------------------------------------------------------------
__global__ __launch_bounds__(256) void scores_gemm(
    const float* __restrict__ qg, const float* __restrict__ kg,
    uint32_t* __restrict__ keyg, int n0, int Nc)
{
    __shared__ float Qs[64][128];   // [d][qrow]  32 KB
    __shared__ float Kb[64][64];    // [d][key]   16 KB
    const int tid = threadIdx.x;
    const int bh = blockIdx.z;
    const int rowBase = n0 + blockIdx.y * 128;   // global n of tile row 0
    const int colBase = blockIdx.x * 64;         // key index of tile col 0
    const int tx = tid & 15, ty = tid >> 4;      // ty 0..15

    // stage Q tile transposed (thread: row = tid&127, 8 float4s along d)
    {
        const int arow = tid & 127, g = tid >> 7;   // g in {0,1}
        const float* qrow = &qg[((size_t)bh * NSEQ + rowBase + arow) * DHEAD];
#pragma unroll
        for (int j = 0; j < 8; j++) {
            int f = g * 8 + j;
            float4 v = *reinterpret_cast<const float4*>(qrow + f * 4);
            Qs[f * 4 + 0][arow] = v.x; Qs[f * 4 + 1][arow] = v.y;
            Qs[f * 4 + 2][arow] = v.z; Qs[f * 4 + 3][arow] = v.w;
        }
    }
    // stage K tile transposed (thread: key = tid&63, 4 float4s along d)
    {
        const int j = tid & 63, g = tid >> 6;       // g in 0..3
        const float* krow = &kg[((size_t)bh * NSEQ + colBase + j) * DHEAD];
#pragma unroll
        for (int i = 0; i < 4; i++) {
            int f = g * 4 + i;
            float4 v = *reinterpret_cast<const float4*>(krow + f * 4);
            Kb[f * 4 + 0][j] = v.x; Kb[f * 4 + 1][j] = v.y;
            Kb[f * 4 + 2][j] = v.z; Kb[f * 4 + 3][j] = v.w;
        }
    }
    __syncthreads();

    float acc[8][4] = {};
#pragma unroll
    for (int kk = 0; kk < 64; kk++) {
        float4 q0 = *reinterpret_cast<const float4*>(&Qs[kk][ty * 8]);
        float4 q1 = *reinterpret_cast<const float4*>(&Qs[kk][ty * 8 + 4]);
        float4 kv = *reinterpret_cast<const float4*>(&Kb[kk][tx * 4]);
        float qr[8] = {q0.x, q0.y, q0.z, q0.w, q1.x, q1.y, q1.z, q1.w};
        float kr[4] = {kv.x, kv.y, kv.z, kv.w};
#pragma unroll
        for (int r = 0; r < 8; r++)
#pragma unroll
            for (int c = 0; c < 4; c++) acc[r][c] += qr[r] * kr[c];
    }

    // encode + store keys (per row: one uint4, wave stores 256B contiguous)
    const size_t rloc0 = (size_t)bh * Nc + (blockIdx.y * 128 + ty * 8);
#pragma unroll
    for (int r = 0; r < 8; r++) {
        uint4 kv4;
        kv4.x = f2key(acc[r][0] * 0.125f);
        kv4.y = f2key(acc[r][1] * 0.125f);
        kv4.z = f2key(acc[r][2] * 0.125f);
        kv4.w = f2key(acc[r][3] * 0.125f);
        *reinterpret_cast<uint4*>(&keyg[(rloc0 + r) * 2048 + colBase + tx * 4]) = kv4;
    }
}

// ---------------------------------------------------------------------------
// Kernel 2b: top-k + softmax from keyg chunk.  1 wave per row, no LDS ->
// high occupancy hides the bisection's serial chain and the key reload.
// ---------------------------------------------------------------------------
__global__ __launch_bounds__(256) void topk_kernel(
    const uint32_t* __restrict__ keyg,
    int* __restrict__ tki, float* __restrict__ tkp, int* __restrict__ tkc,
    int n0, int lgNc)
{
    const int rloc = blockIdx.x * 4 + (threadIdx.x >> 6);
    const int lane = threadIdx.x & 63;
    const int bh = rloc >> lgNc;
    const int n  = n0 + (rloc & ((1 << lgNc) - 1));
    const int row = (bh << 11) + n;
    const uint4* src = reinterpret_cast<const uint4*>(keyg + (size_t)rloc * 2048);

    uint32_t k[32];
#pragma unroll
    for (int p = 0; p < 8; p++) {
        uint4 c4 = src[p * 64 + lane];
        k[p * 4 + 0] = c4.x; k[p * 4 + 1] = c4.y;
        k[p * 4 + 2] = c4.z; k[p * 4 + 3] = c4.w;
    }
    uint32_t km = 0;
#pragma unroll
    for (int t = 0; t < 32; t++) km = k[t] > km ? k[t] : km;
#pragma unroll
    for (int off = 32; off >= 1; off >>= 1) {
        uint32_t o = __shfl_xor(km, off);
        km = o > km ? o : km;
    }
    topk_emit(k, key2f(km), row, lane, tki, tkp, tkc);
}

// ---------------------------------------------------------------------------
// Kernel 2 (fallback, fused via LDS key bounce; R4 design).  Unreachable
// given ws_size >= 210 MB (R10 evidence), kept for safety.
// ---------------------------------------------------------------------------
__global__ __launch_bounds__(256) void scores_topk(
    const float* __restrict__ qg, const float* __restrict__ kg,
    int* __restrict__ tki, float* __restrict__ tkp, int* __restrict__ tkc)
{
    __shared__ float4   Ks[2][2048];
    __shared__ float    qs[8][64];
    __shared__ uint32_t keyk[8][2048];
    const int bh = blockIdx.y;
    const int wave = threadIdx.x >> 6, lane = threadIdx.x & 63;
    const size_t kbase = (size_t)bh * NSEQ * DHEAD;

    if (threadIdx.x < 128) {
        int r = threadIdx.x >> 4, c4 = threadIdx.x & 15;
        *reinterpret_cast<float4*>(&qs[r][c4 << 2]) =
            *reinterpret_cast<const float4*>(
                &qg[((size_t)bh * NSEQ + blockIdx.x * 8 + r) * DHEAD + (c4 << 2)]);
    }

    const int jw  = wave * 4 + (lane >> 4);
    const int swz = lane & 15;
    auto stage = [&](int T, int buf) {
#pragma unroll
        for (int rep = 0; rep < 8; rep++) {
            int j = rep * 16 + jw;
            int c = swz ^ (j & 7);
            gload_lds16(&kg[kbase + (size_t)(T * 128 + j) * DHEAD + (c << 2)],
                        (char*)&Ks[buf][0] + (rep * 4096 + wave * 1024));
        }
    };

    stage(0, 0);
    __syncthreads();

    const int rA = wave * 2, rB = rA + 1;
    float mA = -3.4e38f, mB = -3.4e38f;

    for (int KT = 0; KT < 16; KT++) {
        const int cur = KT & 1;
        if (KT < 15) stage(KT + 1, cur ^ 1);

        float sA0 = 0.f, sA1 = 0.f, sB0 = 0.f, sB1 = 0.f;
#pragma unroll
        for (int c = 0; c < 16; c++) {
            float4 qa = *reinterpret_cast<const float4*>(&qs[rA][c << 2]);
            float4 qb = *reinterpret_cast<const float4*>(&qs[rB][c << 2]);
            int j0 = lane, j1 = 64 + lane;
            float4 kv0 = Ks[cur][(j0 << 4) + (c ^ (j0 & 7))];
            float4 kv1 = Ks[cur][(j1 << 4) + (c ^ (j1 & 7))];
            sA0 += qa.x * kv0.x + qa.y * kv0.y + qa.z * kv0.z + qa.w * kv0.w;
            sA1 += qa.x * kv1.x + qa.y * kv1.y + qa.z * kv1.z + qa.w * kv1.w;
            sB0 += qb.x * kv0.x + qb.y * kv0.y + qb.z * kv0.z + qb.w * kv0.w;
            sB1 += qb.x * kv1.x + qb.y * kv1.y + qb.z * kv1.z + qb.w * kv1.w;
        }
        sA0 *= 0.125f; sA1 *= 0.125f; sB0 *= 0.125f; sB1 *= 0.125f;
        mA = fmaxf(mA, fmaxf(sA0, sA1));
        mB = fmaxf(mB, fmaxf(sB0, sB1));
        keyk[rA][KT * 128 + lane]      = f2key(sA0);
        keyk[rA][KT * 128 + 64 + lane] = f2key(sA1);
        keyk[rB][KT * 128 + lane]      = f2key(sB0);
        keyk[rB][KT * 128 + 64 + lane] = f2key(sB1);
        __syncthreads();
    }

#pragma unroll
    for (int off = 32; off >= 1; off >>= 1) {
        mA = fmaxf(mA, __shfl_xor(mA, off));
        mB = fmaxf(mB, __shfl_xor(mB, off));
    }

    const int rowA = bh * NSEQ + blockIdx.x * 8 + wave * 2;
    {
        const uint4* src = reinterpret_cast<const uint4*>(&keyk[rA][0]);
        uint32_t k[32];
#pragma unroll
        for (int p = 0; p < 8; p++) {
            uint4 c4 = src[p * 64 + lane];
            k[p * 4 + 0] = c4.x; k[p * 4 + 1] = c4.y;
            k[p * 4 + 2] = c4.z; k[p * 4 + 3] = c4.w;
        }
        topk_emit(k, mA, rowA, lane, tki, tkp, tkc);
    }
    {
        const uint4* src = reinterpret_cast<const uint4*>(&keyk[rB][0]);
        uint32_t k[32];
#pragma unroll
        for (int p = 0; p < 8; p++) {
            uint4 c4 = src[p * 64 + lane];
            k[p * 4 + 0] = c4.x; k[p * 4 + 1] = c4.y;
            k[p * 4 + 2] = c4.z; k[p * 4 + 3] = c4.w;
        }
        topk_emit(k, mB, rowA + 1, lane, tki, tkp, tkc);
    }
}

// ---------------------------------------------------------------------------
// Kernel 3: one propagation step.  v_out[n] = sum_j p[n,j] * v_in[idx[n,j]];
// res(+)= sigmoid(alphas_raw[iter,h]) * v_out, res in [B,N,H*DH] layout.
// idx/prob loads vectorized (CAP=68 -> 272B row stride, 16B-aligned).
// ---------------------------------------------------------------------------
__global__ __launch_bounds__(256) void prop(
    const float* __restrict__ vin, float* __restrict__ vout,
    float* __restrict__ res, const float* __restrict__ araw,
    const int* __restrict__ tki, const float* __restrict__ tkp,
    const int* __restrict__ tkc, int iter)
{
    const int row = blockIdx.x * 4 + (threadIdx.x >> 6);
    const int lane = threadIdx.x & 63;
    const int bh = row >> 11;
    const int h = bh & 15;
    const int cnt = tkc[row];
    const int* idx = tki + (size_t)row * CAP;
    const float* pr = tkp + (size_t)row * CAP;
    const float* vb = vin + (size_t)bh * NSEQ * DHEAD;

    float a0 = 0.f, a1 = 0.f, a2 = 0.f, a3 = 0.f;
    int j = 0;
    for (; j + 4 <= cnt; j += 4) {
        int4   i4 = *reinterpret_cast<const int4*>(&idx[j]);
        float4 p4 = *reinterpret_cast<const float4*>(&pr[j]);
        a0 += p4.x * vb[(size_t)i4.x * DHEAD + lane];
        a1 += p4.y * vb[(size_t)i4.y * DHEAD + lane];
        a2 += p4.z * vb[(size_t)i4.z * DHEAD + lane];
        a3 += p4.w * vb[(size_t)i4.w * DHEAD + lane];
    }
    for (; j < cnt; j++) a0 += pr[j] * vb[(size_t)idx[j] * DHEAD + lane];
    float acc = (a0 + a1) + (a2 + a3);

    vout[(size_t)row * DHEAD + lane] = acc;

    float ar = araw[iter * HHEADS + h];
    float alpha = 1.f / (1.f + __expf(-ar));
    const int b = row >> 15, n = row & 2047;
    size_t ro = ((size_t)(b * NSEQ + n)) * 1024 + h * DHEAD + lane;
    if (iter == 1) res[ro] = alpha * acc;
    else           res[ro] += alpha * acc;
}

// ---------------------------------------------------------------------------
// Kernel 4: output GEMM.  res[4096,1024] @ Wout[1024,1024] + bout -> out
// 128x64 tile, 8x4 micro-tile, BK=32 (512 blocks -> 2/CU).  Kept from R12
// (net win vs 64x64).  Ascending-k chain -> bit-identical.
// ---------------------------------------------------------------------------
__global__ __launch_bounds__(256) void out_gemm(
    const float* __restrict__ A, const float* __restrict__ W,
    const float* __restrict__ bias, float* __restrict__ out)
{
    __shared__ float As[32][128];   // 16 KB
    __shared__ float Bs[32][64];    // 8 KB
    const int tid = threadIdx.x;
    const int rowBase = blockIdx.y * 128;
    const int colBase = blockIdx.x * 64;
    const int tx = tid & 15, ty = tid >> 4;
    const int arow = tid & 127, ag = (tid >> 7) << 4;   // A: row, k-half {0,16}
    const int bkk = tid >> 4,  bc4 = tid & 15;          // B: k-row 0..15, col f4

    float acc[8][4] = {};
    float4 ap[4], bp[2];
    const float* Arow = &A[(size_t)(rowBase + arow) * 1024];
#pragma unroll
    for (int j = 0; j < 4; j++)
        ap[j] = *reinterpret_cast<const float4*>(Arow + ag + j * 4);
#pragma unroll
    for (int i = 0; i < 2; i++)
        bp[i] = *reinterpret_cast<const float4*>(&W[(size_t)(bkk + 16 * i) * 1024 + colBase + bc4 * 4]);

    for (int k0 = 0; k0 < 1024; k0 += 32) {
        __syncthreads();
#pragma unroll
        for (int j = 0; j < 4; j++) {
            As[ag + j * 4 + 0][arow] = ap[j].x;
            As[ag + j * 4 + 1][arow] = ap[j].y;
            As[ag + j * 4 + 2][arow] = ap[j].z;
            As[ag + j * 4 + 3][arow] = ap[j].w;
        }
#pragma unroll
        for (int i = 0; i < 2; i++)
            *reinterpret_cast<float4*>(&Bs[bkk + 16 * i][bc4 * 4]) = bp[i];
        __syncthreads();
        if (k0 + 32 < 1024) {
#pragma unroll
            for (int j = 0; j < 4; j++)
                ap[j] = *reinterpret_cast<const float4*>(Arow + k0 + 32 + ag + j * 4);
#pragma unroll
            for (int i = 0; i < 2; i++)
                bp[i] = *reinterpret_cast<const float4*>(&W[(size_t)(k0 + 32 + bkk + 16 * i) * 1024 + colBase + bc4 * 4]);
        }
#pragma unroll
        for (int kk = 0; kk < 32; kk++) {
            float4 a0 = *reinterpret_cast<const float4*>(&As[kk][ty * 8]);
            float4 a1 = *reinterpret_cast<const float4*>(&As[kk][ty * 8 + 4]);
            float4 bv = *reinterpret_cast<const float4*>(&Bs[kk][tx * 4]);
            float qr[8] = {a0.x, a0.y, a0.z, a0.w, a1.x, a1.y, a1.z, a1.w};
            float br[4] = {bv.x, bv.y, bv.z, bv.w};
#pragma unroll
            for (int r = 0; r < 8; r++)
#pragma unroll
                for (int c = 0; c < 4; c++) acc[r][c] += qr[r] * br[c];
        }
    }

    float4 bb = *reinterpret_cast<const float4*>(&bias[colBase + tx * 4]);
#pragma unroll
    for (int r = 0; r < 8; r++) {
        int row = rowBase + ty * 8 + r;
        float4 st;
        st.x = acc[r][0] + bb.x; st.y = acc[r][1] + bb.y;
        st.z = acc[r][2] + bb.z; st.w = acc[r][3] + bb.w;
        *reinterpret_cast<float4*>(&out[(size_t)row * 1024 + colBase + tx * 4]) = st;
    }
}

// ---------------------------------------------------------------------------
extern "C" void kernel_launch(void* const* d_in, const int* in_sizes, int n_in,
                              void* d_out, int out_size, void* d_ws, size_t ws_size,
                              hipStream_t stream)
{
    const float* x    = (const float*)d_in[0];
    const float* Wqkv = (const float*)d_in[1];
    const float* bqkv = (const float*)d_in[2];
    const float* Wout = (const float*)d_in[3];
    const float* bout = (const float*)d_in[4];
    const float* araw = (const float*)d_in[5];
    float* out = (float*)d_out;

    const size_t SEG = (size_t)1 << 22;   // 4M floats = one [B,H,N,DH] tensor
    float* ws = (float*)d_ws;
    float* q   = ws;                // [0, 16MB)
    float* k   = q + SEG;           // [16, 32MB)
    float* v   = k + SEG;           // [32, 48MB)
    int*   tki = (int*)(v + SEG);                   // 65536*68 ints (17.8MB)
    float* tkp = (float*)(tki + (size_t)NROWS * CAP);
    int*   tkc = (int*)(tkp + (size_t)NROWS * CAP);
    uint32_t* keyg = (uint32_t*)(tkc + NROWS);      // chunked key scratch
    float* vA  = (float*)keyg;      // keyg dead before prop1; alias (16MB)
    float* res = q;                 // q dead after scores; alias

    const size_t keyg_off = (size_t)((char*)keyg - (char*)d_ws);
    const size_t leftover = ws_size > keyg_off ? ws_size - keyg_off : 0;

    // largest power-of-two Nc (query positions per chunk) whose keyg fits:
    // bytes(Nc) = 32 slices * Nc rows * 2048 keys * 4B = Nc << 18
    int Nc = NSEQ;
    while (Nc >= 128 && (((size_t)Nc) << 18) > leftover) Nc >>= 1;

    qkv_gemm<<<dim3(24, 32), 256, 0, stream>>>(x, Wqkv, bqkv, q, k, v);

    if (Nc >= 128) {
        int lgNc = __builtin_ctz((unsigned)Nc);
        for (int n0 = 0; n0 < NSEQ; n0 += Nc) {
            scores_gemm<<<dim3(32, Nc / 128, 32), 256, 0, stream>>>(q, k, keyg, n0, Nc);
            topk_kernel<<<dim3(32 * Nc / 4), 256, 0, stream>>>(keyg, tki, tkp, tkc, n0, lgNc);
        }
    } else {
        scores_topk<<<dim3(256, 32), 256, 0, stream>>>(q, k, tki, tkp, tkc);
    }

    prop<<<dim3(NROWS / 4), 256, 0, stream>>>(v,  vA, res, araw, tki, tkp, tkc, 1);
    prop<<<dim3(NROWS / 4), 256, 0, stream>>>(vA, v,  res, araw, tki, tkp, tkc, 2);
    prop<<<dim3(NROWS / 4), 256, 0, stream>>>(v,  vA, res, araw, tki, tkp, tkc, 3);
    out_gemm<<<dim3(16, 32), 256, 0, stream>>>(res, Wout, bout, out);
}

// Round 14
// 1156.769 us; speedup vs baseline: 1.0926x; 1.0595x over previous
//
#include <hip/hip_runtime.h>
#include <cstdint>
#include <cstddef>

#define HHEADS 16
#define DHEAD  64
#define NSEQ   2048
#define NBATCH 2
#define NDIM   1024
#define TOPKN  64
#define CAP    68
#define NROWS  (NBATCH*HHEADS*NSEQ)   // 65536

// ---------------------------------------------------------------------------
// Kernel 1: QKV GEMM.  x[4096,1024] @ Wqkv[1024,3072] + bqkv
// -> q,k,v each laid out [B,H,N,DH].  128x128 tile, 8x8 micro-tile, BK=16
// (R8-proven: 312 us, VALUBusy 69%, 0 bank conflicts; BK=32 regressed).
// ---------------------------------------------------------------------------
__global__ __launch_bounds__(256) void qkv_gemm(
    const float* __restrict__ x, const float* __restrict__ W,
    const float* __restrict__ bias,
    float* __restrict__ qout, float* __restrict__ kout, float* __restrict__ vout)
{
    __shared__ float As[16][128];   // transposed A tile
    __shared__ float Bs[16][128];
    const int tid = threadIdx.x;
    const int rowBase = blockIdx.y * 128;
    const int colBase = blockIdx.x * 128;
    const int tx = tid & 15, ty = tid >> 4;
    const int arow = tid & 127, akq = tid >> 7;     // A: row, k-quarter (0/1)
    const int bkk = tid >> 5,  bc4 = tid & 31;      // B: kk row, col float4

    float acc[8][8] = {};
    float4 a0 = *reinterpret_cast<const float4*>(&x[(size_t)(rowBase + arow) * NDIM + akq * 4]);
    float4 a1 = *reinterpret_cast<const float4*>(&x[(size_t)(rowBase + arow) * NDIM + (akq + 2) * 4]);
    float4 b0 = *reinterpret_cast<const float4*>(&W[(size_t)bkk * 3072 + colBase + bc4 * 4]);
    float4 b1 = *reinterpret_cast<const float4*>(&W[(size_t)(bkk + 8) * 3072 + colBase + bc4 * 4]);

    for (int k0 = 0; k0 < NDIM; k0 += 16) {
        __syncthreads();   // previous tile's compute done
        As[akq * 4 + 0][arow] = a0.x; As[akq * 4 + 1][arow] = a0.y;
        As[akq * 4 + 2][arow] = a0.z; As[akq * 4 + 3][arow] = a0.w;
        As[(akq + 2) * 4 + 0][arow] = a1.x; As[(akq + 2) * 4 + 1][arow] = a1.y;
        As[(akq + 2) * 4 + 2][arow] = a1.z; As[(akq + 2) * 4 + 3][arow] = a1.w;
        *reinterpret_cast<float4*>(&Bs[bkk][bc4 * 4])     = b0;
        *reinterpret_cast<float4*>(&Bs[bkk + 8][bc4 * 4]) = b1;
        __syncthreads();   // staged
        if (k0 + 16 < NDIM) {   // prefetch next tile; latency hidden by compute
            a0 = *reinterpret_cast<const float4*>(&x[(size_t)(rowBase + arow) * NDIM + k0 + 16 + akq * 4]);
            a1 = *reinterpret_cast<const float4*>(&x[(size_t)(rowBase + arow) * NDIM + k0 + 16 + (akq + 2) * 4]);
            b0 = *reinterpret_cast<const float4*>(&W[(size_t)(k0 + 16 + bkk) * 3072 + colBase + bc4 * 4]);
            b1 = *reinterpret_cast<const float4*>(&W[(size_t)(k0 + 16 + bkk + 8) * 3072 + colBase + bc4 * 4]);
        }
#pragma unroll
        for (int kk = 0; kk < 16; kk++) {
            float4 alo = *reinterpret_cast<const float4*>(&As[kk][ty * 4]);
            float4 ahi = *reinterpret_cast<const float4*>(&As[kk][64 + ty * 4]);
            float4 blo = *reinterpret_cast<const float4*>(&Bs[kk][tx * 4]);
            float4 bhi = *reinterpret_cast<const float4*>(&Bs[kk][64 + tx * 4]);
            float ar[8] = {alo.x, alo.y, alo.z, alo.w, ahi.x, ahi.y, ahi.z, ahi.w};
            float br[8] = {blo.x, blo.y, blo.z, blo.w, bhi.x, bhi.y, bhi.z, bhi.w};
#pragma unroll
            for (int i = 0; i < 8; i++)
#pragma unroll
                for (int j = 0; j < 8; j++) acc[i][j] += ar[i] * br[j];
        }
    }

    const int which = colBase >> 10;
    float* dst = which == 0 ? qout : (which == 1 ? kout : vout);
#pragma unroll
    for (int jh = 0; jh < 2; jh++) {
        const int colh = colBase + jh * 64 + tx * 4;
        const int h = (colh & 1023) >> 6;
        const int d0 = colh & 63;
        float4 bb = *reinterpret_cast<const float4*>(&bias[colh]);
#pragma unroll
        for (int ih = 0; ih < 2; ih++)
#pragma unroll
            for (int i = 0; i < 4; i++) {
                int r = rowBase + ih * 64 + ty * 4 + i;
                int b = r >> 11, n = r & 2047;
                size_t o = ((size_t)((b << 4) + h) * NSEQ + n) * DHEAD + d0;
                float4 st;
                st.x = acc[ih * 4 + i][jh * 4 + 0] + bb.x;
                st.y = acc[ih * 4 + i][jh * 4 + 1] + bb.y;
                st.z = acc[ih * 4 + i][jh * 4 + 2] + bb.z;
                st.w = acc[ih * 4 + i][jh * 4 + 3] + bb.w;
                *reinterpret_cast<float4*>(&dst[o]) = st;
            }
    }
}

// ---------------------------------------------------------------------------
// order-preserving float<->uint key transforms
// ---------------------------------------------------------------------------
__device__ __forceinline__ uint32_t f2key(float f) {
    uint32_t u = __float_as_uint(f);
    return (u & 0x80000000u) ? ~u : (u | 0x80000000u);
}
__device__ __forceinline__ float key2f(uint32_t k) {
    uint32_t u = (k & 0x80000000u) ? (k & 0x7FFFFFFFu) : ~k;
    return __uint_as_float(u);
}

// Per-row top-64 + softmax + compacted emit, entirely from 32 key registers.
// Bisection brackets [lo0, hi0] must satisfy count(>=lo0) >= 64 and
// hi0 >= key64; converges to the exact 64th-largest key regardless.
__device__ __forceinline__ void topk_emit(
    uint32_t (&k)[32], float m, uint32_t lo0, uint32_t hi0, int row, int lane,
    int* __restrict__ tki, float* __restrict__ tkp, int* __restrict__ tkc)
{
    // bisection for the 64th-largest key (ballot count, wave-uniform scalar)
    uint32_t lo = lo0, hi = hi0;
    while (lo < hi) {
        uint32_t mid = (uint32_t)(((uint64_t)lo + (uint64_t)hi + 1ull) >> 1);
        int c = 0;
#pragma unroll
        for (int t = 0; t < 32; t++)
            c += (int)__popcll(__ballot(k[t] >= mid));
        if (c >= TOPKN) { lo = mid; if (c == TOPKN) { hi = mid; } }
        else hi = mid - 1;
    }
    const uint32_t thr = lo;

    // softmax over kept entries (overwrite k[t] with exp bits; keep mask)
    uint32_t keep = 0;
    float sum = 0.f;
#pragma unroll
    for (int t = 0; t < 32; t++) {
        bool kp = (k[t] >= thr);
        float e = kp ? __expf(key2f(k[t]) - m) : 0.f;
        k[t] = __float_as_uint(e);
        sum += e;
        keep |= kp ? (1u << t) : 0u;
    }
#pragma unroll
    for (int off = 32; off >= 1; off >>= 1) sum += __shfl_xor(sum, off);
    const float rs = 1.f / sum;

    // compacted emit
    int base = 0;
    const unsigned long long below = (1ull << lane) - 1ull;
#pragma unroll
    for (int t = 0; t < 32; t++) {
        bool kp = (keep >> t) & 1u;
        unsigned long long mask = __ballot(kp);
        if (kp) {
            int pos = base + (int)__popcll(mask & below);
            if (pos < CAP) {
                tki[(size_t)row * CAP + pos] = ((t >> 2) << 8) + (lane << 2) + (t & 3);
                tkp[(size_t)row * CAP + pos] = __uint_as_float(k[t]) * rs;
            }
        }
        base += (int)__popcll(mask);
    }
    if (lane == 0) tkc[row] = base < CAP ? base : CAP;
}

// direct global->LDS 16B copy (no VGPR round-trip). lds base must be
// wave-uniform; HW scatters lane i to base + i*16 (m104/m108).
__device__ __forceinline__ void gload_lds16(const void* g, void* l) {
    __builtin_amdgcn_global_load_lds(
        (const __attribute__((address_space(1))) unsigned int*)g,
        (__attribute__((address_space(3))) unsigned int*)l,
        16, 0, 0);
}

// ---------------------------------------------------------------------------
// Kernel 2a: scores as a GEMM.  Per (b,h): S = Q[2048x64] @ K^T[64x2048].
// Tile 128(q) x 64(key), K-depth = 64 = ONE stage, ONE barrier, no k-loop.
// Micro-tile 8x4: per kk, 3 ds_read_b128 feed 32 FMAs.  Keys f2key(s*0.125)
// stream to chunked keyg.  d-accumulation single ascending chain.
// ---------------------------------------------------------------------------
__global__ __launch_bounds__(256) void scores_gemm(
    const float* __restrict__ qg, const float* __restrict__ kg,
    uint32_t* __restrict__ keyg, int n0, int Nc)
{
    __shared__ float Qs[64][128];   // [d][qrow]  32 KB
    __shared__ float Kb[64][64];    // [d][key]   16 KB
    const int tid = threadIdx.x;
    const int bh = blockIdx.z;
    const int rowBase = n0 + blockIdx.y * 128;   // global n of tile row 0
    const int colBase = blockIdx.x * 64;         // key index of tile col 0
    const int tx = tid & 15, ty = tid >> 4;      // ty 0..15

    // stage Q tile transposed (thread: row = tid&127, 8 float4s along d)
    {
        const int arow = tid & 127, g = tid >> 7;   // g in {0,1}
        const float* qrow = &qg[((size_t)bh * NSEQ + rowBase + arow) * DHEAD];
#pragma unroll
        for (int j = 0; j < 8; j++) {
            int f = g * 8 + j;
            float4 v = *reinterpret_cast<const float4*>(qrow + f * 4);
            Qs[f * 4 + 0][arow] = v.x; Qs[f * 4 + 1][arow] = v.y;
            Qs[f * 4 + 2][arow] = v.z; Qs[f * 4 + 3][arow] = v.w;
        }
    }
    // stage K tile transposed (thread: key = tid&63, 4 float4s along d)
    {
        const int j = tid & 63, g = tid >> 6;       // g in 0..3
        const float* krow = &kg[((size_t)bh * NSEQ + colBase + j) * DHEAD];
#pragma unroll
        for (int i = 0; i < 4; i++) {
            int f = g * 4 + i;
            float4 v = *reinterpret_cast<const float4*>(krow + f * 4);
            Kb[f * 4 + 0][j] = v.x; Kb[f * 4 + 1][j] = v.y;
            Kb[f * 4 + 2][j] = v.z; Kb[f * 4 + 3][j] = v.w;
        }
    }
    __syncthreads();

    float acc[8][4] = {};
#pragma unroll
    for (int kk = 0; kk < 64; kk++) {
        float4 q0 = *reinterpret_cast<const float4*>(&Qs[kk][ty * 8]);
        float4 q1 = *reinterpret_cast<const float4*>(&Qs[kk][ty * 8 + 4]);
        float4 kv = *reinterpret_cast<const float4*>(&Kb[kk][tx * 4]);
        float qr[8] = {q0.x, q0.y, q0.z, q0.w, q1.x, q1.y, q1.z, q1.w};
        float kr[4] = {kv.x, kv.y, kv.z, kv.w};
#pragma unroll
        for (int r = 0; r < 8; r++)
#pragma unroll
            for (int c = 0; c < 4; c++) acc[r][c] += qr[r] * kr[c];
    }

    // encode + store keys (per row: one uint4, wave stores 256B contiguous)
    const size_t rloc0 = (size_t)bh * Nc + (blockIdx.y * 128 + ty * 8);
#pragma unroll
    for (int r = 0; r < 8; r++) {
        uint4 kv4;
        kv4.x = f2key(acc[r][0] * 0.125f);
        kv4.y = f2key(acc[r][1] * 0.125f);
        kv4.z = f2key(acc[r][2] * 0.125f);
        kv4.w = f2key(acc[r][3] * 0.125f);
        *reinterpret_cast<uint4*>(&keyg[(rloc0 + r) * 2048 + colBase + tx * 4]) = kv4;
    }
}

// ---------------------------------------------------------------------------
// Kernel 2b: top-k + softmax from keyg chunk.  1 wave per row, no LDS.
// Bracketed bisection: lo = wave-min of lane maxes (>=64 values above it),
// hi = global max.  Exact: converges to the identical 64th-largest key.
// ---------------------------------------------------------------------------
__global__ __launch_bounds__(256) void topk_kernel(
    const uint32_t* __restrict__ keyg,
    int* __restrict__ tki, float* __restrict__ tkp, int* __restrict__ tkc,
    int n0, int lgNc)
{
    const int rloc = blockIdx.x * 4 + (threadIdx.x >> 6);
    const int lane = threadIdx.x & 63;
    const int bh = rloc >> lgNc;
    const int n  = n0 + (rloc & ((1 << lgNc) - 1));
    const int row = (bh << 11) + n;
    const uint4* src = reinterpret_cast<const uint4*>(keyg + (size_t)rloc * 2048);

    uint32_t k[32];
#pragma unroll
    for (int p = 0; p < 8; p++) {
        uint4 c4 = src[p * 64 + lane];
        k[p * 4 + 0] = c4.x; k[p * 4 + 1] = c4.y;
        k[p * 4 + 2] = c4.z; k[p * 4 + 3] = c4.w;
    }
    // lane max, then wave max (softmax m / hi) and wave min-of-lane-max (lo)
    uint32_t lmax = 0;
#pragma unroll
    for (int t = 0; t < 32; t++) lmax = k[t] > lmax ? k[t] : lmax;
    uint32_t wmax = lmax, wmin = lmax;
#pragma unroll
    for (int off = 32; off >= 1; off >>= 1) {
        uint32_t a = __shfl_xor(wmax, off);
        uint32_t b = __shfl_xor(wmin, off);
        wmax = a > wmax ? a : wmax;
        wmin = b < wmin ? b : wmin;
    }
    topk_emit(k, key2f(wmax), wmin, wmax, row, lane, tki, tkp, tkc);
}

// ---------------------------------------------------------------------------
// Kernel 2 (fallback, fused via LDS key bounce; R4 design).  Unreachable
// given ws_size >= 210 MB (R10 evidence), kept for safety.
// ---------------------------------------------------------------------------
__global__ __launch_bounds__(256) void scores_topk(
    const float* __restrict__ qg, const float* __restrict__ kg,
    int* __restrict__ tki, float* __restrict__ tkp, int* __restrict__ tkc)
{
    __shared__ float4   Ks[2][2048];
    __shared__ float    qs[8][64];
    __shared__ uint32_t keyk[8][2048];
    const int bh = blockIdx.y;
    const int wave = threadIdx.x >> 6, lane = threadIdx.x & 63;
    const size_t kbase = (size_t)bh * NSEQ * DHEAD;

    if (threadIdx.x < 128) {
        int r = threadIdx.x >> 4, c4 = threadIdx.x & 15;
        *reinterpret_cast<float4*>(&qs[r][c4 << 2]) =
            *reinterpret_cast<const float4*>(
                &qg[((size_t)bh * NSEQ + blockIdx.x * 8 + r) * DHEAD + (c4 << 2)]);
    }

    const int jw  = wave * 4 + (lane >> 4);
    const int swz = lane & 15;
    auto stage = [&](int T, int buf) {
#pragma unroll
        for (int rep = 0; rep < 8; rep++) {
            int j = rep * 16 + jw;
            int c = swz ^ (j & 7);
            gload_lds16(&kg[kbase + (size_t)(T * 128 + j) * DHEAD + (c << 2)],
                        (char*)&Ks[buf][0] + (rep * 4096 + wave * 1024));
        }
    };

    stage(0, 0);
    __syncthreads();

    const int rA = wave * 2, rB = rA + 1;
    float mA = -3.4e38f, mB = -3.4e38f;

    for (int KT = 0; KT < 16; KT++) {
        const int cur = KT & 1;
        if (KT < 15) stage(KT + 1, cur ^ 1);

        float sA0 = 0.f, sA1 = 0.f, sB0 = 0.f, sB1 = 0.f;
#pragma unroll
        for (int c = 0; c < 16; c++) {
            float4 qa = *reinterpret_cast<const float4*>(&qs[rA][c << 2]);
            float4 qb = *reinterpret_cast<const float4*>(&qs[rB][c << 2]);
            int j0 = lane, j1 = 64 + lane;
            float4 kv0 = Ks[cur][(j0 << 4) + (c ^ (j0 & 7))];
            float4 kv1 = Ks[cur][(j1 << 4) + (c ^ (j1 & 7))];
            sA0 += qa.x * kv0.x + qa.y * kv0.y + qa.z * kv0.z + qa.w * kv0.w;
            sA1 += qa.x * kv1.x + qa.y * kv1.y + qa.z * kv1.z + qa.w * kv1.w;
            sB0 += qb.x * kv0.x + qb.y * kv0.y + qb.z * kv0.z + qb.w * kv0.w;
            sB1 += qb.x * kv1.x + qb.y * kv1.y + qb.z * kv1.z + qb.w * kv1.w;
        }
        sA0 *= 0.125f; sA1 *= 0.125f; sB0 *= 0.125f; sB1 *= 0.125f;
        mA = fmaxf(mA, fmaxf(sA0, sA1));
        mB = fmaxf(mB, fmaxf(sB0, sB1));
        keyk[rA][KT * 128 + lane]      = f2key(sA0);
        keyk[rA][KT * 128 + 64 + lane] = f2key(sA1);
        keyk[rB][KT * 128 + lane]      = f2key(sB0);
        keyk[rB][KT * 128 + 64 + lane] = f2key(sB1);
        __syncthreads();
    }

#pragma unroll
    for (int off = 32; off >= 1; off >>= 1) {
        mA = fmaxf(mA, __shfl_xor(mA, off));
        mB = fmaxf(mB, __shfl_xor(mB, off));
    }

    const int rowA = bh * NSEQ + blockIdx.x * 8 + wave * 2;
    {
        const uint4* src = reinterpret_cast<const uint4*>(&keyk[rA][0]);
        uint32_t k[32];
#pragma unroll
        for (int p = 0; p < 8; p++) {
            uint4 c4 = src[p * 64 + lane];
            k[p * 4 + 0] = c4.x; k[p * 4 + 1] = c4.y;
            k[p * 4 + 2] = c4.z; k[p * 4 + 3] = c4.w;
        }
        topk_emit(k, mA, 0u, 0xFFFFFFFFu, rowA, lane, tki, tkp, tkc);
    }
    {
        const uint4* src = reinterpret_cast<const uint4*>(&keyk[rB][0]);
        uint32_t k[32];
#pragma unroll
        for (int p = 0; p < 8; p++) {
            uint4 c4 = src[p * 64 + lane];
            k[p * 4 + 0] = c4.x; k[p * 4 + 1] = c4.y;
            k[p * 4 + 2] = c4.z; k[p * 4 + 3] = c4.w;
        }
        topk_emit(k, mB, 0u, 0xFFFFFFFFu, rowA + 1, lane, tki, tkp, tkc);
    }
}

// ---------------------------------------------------------------------------
// Kernel 3: one propagation step.  v_out[n] = sum_j p[n,j] * v_in[idx[n,j]];
// res(+)= sigmoid(alphas_raw[iter,h]) * v_out, res in [B,N,H*DH] layout.
// idx/prob loads vectorized (CAP=68 -> 272B row stride, 16B-aligned).
// ---------------------------------------------------------------------------
__global__ __launch_bounds__(256) void prop(
    const float* __restrict__ vin, float* __restrict__ vout,
    float* __restrict__ res, const float* __restrict__ araw,
    const int* __restrict__ tki, const float* __restrict__ tkp,
    const int* __restrict__ tkc, int iter)
{
    const int row = blockIdx.x * 4 + (threadIdx.x >> 6);
    const int lane = threadIdx.x & 63;
    const int bh = row >> 11;
    const int h = bh & 15;
    const int cnt = tkc[row];
    const int* idx = tki + (size_t)row * CAP;
    const float* pr = tkp + (size_t)row * CAP;
    const float* vb = vin + (size_t)bh * NSEQ * DHEAD;

    float a0 = 0.f, a1 = 0.f, a2 = 0.f, a3 = 0.f;
    int j = 0;
    for (; j + 4 <= cnt; j += 4) {
        int4   i4 = *reinterpret_cast<const int4*>(&idx[j]);
        float4 p4 = *reinterpret_cast<const float4*>(&pr[j]);
        a0 += p4.x * vb[(size_t)i4.x * DHEAD + lane];
        a1 += p4.y * vb[(size_t)i4.y * DHEAD + lane];
        a2 += p4.z * vb[(size_t)i4.z * DHEAD + lane];
        a3 += p4.w * vb[(size_t)i4.w * DHEAD + lane];
    }
    for (; j < cnt; j++) a0 += pr[j] * vb[(size_t)idx[j] * DHEAD + lane];
    float acc = (a0 + a1) + (a2 + a3);

    vout[(size_t)row * DHEAD + lane] = acc;

    float ar = araw[iter * HHEADS + h];
    float alpha = 1.f / (1.f + __expf(-ar));
    const int b = row >> 15, n = row & 2047;
    size_t ro = ((size_t)(b * NSEQ + n)) * 1024 + h * DHEAD + lane;
    if (iter == 1) res[ro] = alpha * acc;
    else           res[ro] += alpha * acc;
}

// ---------------------------------------------------------------------------
// Kernel 4: output GEMM.  res[4096,1024] @ Wout[1024,1024] + bout -> out
// 64x64 tile, 4x4 micro-tile (1024 blocks -> high occupancy; R11-proven).
// ---------------------------------------------------------------------------
__global__ __launch_bounds__(256) void out_gemm(
    const float* __restrict__ A, const float* __restrict__ W,
    const float* __restrict__ bias, float* __restrict__ out)
{
    __shared__ float As[16][64];
    __shared__ float Bs[16][64];
    const int tid = threadIdx.x;
    const int rowBase = blockIdx.y * 64;
    const int colBase = blockIdx.x * 64;
    const int tx = tid & 15, ty = tid >> 4;
    const int aRow = tid >> 2, aCol = (tid & 3) << 2;
    const int bRow = tid >> 4, bCol = (tid & 15) << 2;

    float acc[4][4] = {};
    for (int k0 = 0; k0 < 1024; k0 += 16) {
        float4 av = *reinterpret_cast<const float4*>(&A[(size_t)(rowBase + aRow) * 1024 + k0 + aCol]);
        float4 bv = *reinterpret_cast<const float4*>(&W[(size_t)(k0 + bRow) * 1024 + colBase + bCol]);
        __syncthreads();
        As[aCol + 0][aRow] = av.x; As[aCol + 1][aRow] = av.y;
        As[aCol + 2][aRow] = av.z; As[aCol + 3][aRow] = av.w;
        *reinterpret_cast<float4*>(&Bs[bRow][bCol]) = bv;
        __syncthreads();
#pragma unroll
        for (int kk = 0; kk < 16; kk++) {
            float4 a4 = *reinterpret_cast<const float4*>(&As[kk][ty << 2]);
            float4 b4 = *reinterpret_cast<const float4*>(&Bs[kk][tx << 2]);
            float ar[4] = {a4.x, a4.y, a4.z, a4.w};
            float br[4] = {b4.x, b4.y, b4.z, b4.w};
#pragma unroll
            for (int i = 0; i < 4; i++)
#pragma unroll
                for (int j = 0; j < 4; j++) acc[i][j] += ar[i] * br[j];
        }
    }
    float4 bb = *reinterpret_cast<const float4*>(&bias[colBase + (tx << 2)]);
#pragma unroll
    for (int i = 0; i < 4; i++) {
        int r = rowBase + (ty << 2) + i;
        float4 st;
        st.x = acc[i][0] + bb.x; st.y = acc[i][1] + bb.y;
        st.z = acc[i][2] + bb.z; st.w = acc[i][3] + bb.w;
        *reinterpret_cast<float4*>(&out[(size_t)r * 1024 + colBase + (tx << 2)]) = st;
    }
}

// ---------------------------------------------------------------------------
extern "C" void kernel_launch(void* const* d_in, const int* in_sizes, int n_in,
                              void* d_out, int out_size, void* d_ws, size_t ws_size,
                              hipStream_t stream)
{
    const float* x    = (const float*)d_in[0];
    const float* Wqkv = (const float*)d_in[1];
    const float* bqkv = (const float*)d_in[2];
    const float* Wout = (const float*)d_in[3];
    const float* bout = (const float*)d_in[4];
    const float* araw = (const float*)d_in[5];
    float* out = (float*)d_out;

    const size_t SEG = (size_t)1 << 22;   // 4M floats = one [B,H,N,DH] tensor
    float* ws = (float*)d_ws;
    float* q   = ws;                // [0, 16MB)
    float* k   = q + SEG;           // [16, 32MB)
    float* v   = k + SEG;           // [32, 48MB)
    int*   tki = (int*)(v + SEG);                   // 65536*68 ints (17.8MB)
    float* tkp = (float*)(tki + (size_t)NROWS * CAP);
    int*   tkc = (int*)(tkp + (size_t)NROWS * CAP);
    uint32_t* keyg = (uint32_t*)(tkc + NROWS);      // chunked key scratch
    float* vA  = (float*)keyg;      // keyg dead before prop1; alias (16MB)
    float* res = q;                 // q dead after scores; alias

    const size_t keyg_off = (size_t)((char*)keyg - (char*)d_ws);
    const size_t leftover = ws_size > keyg_off ? ws_size - keyg_off : 0;

    // largest power-of-two Nc (query positions per chunk) whose keyg fits:
    // bytes(Nc) = 32 slices * Nc rows * 2048 keys * 4B = Nc << 18
    int Nc = NSEQ;
    while (Nc >= 128 && (((size_t)Nc) << 18) > leftover) Nc >>= 1;

    qkv_gemm<<<dim3(24, 32), 256, 0, stream>>>(x, Wqkv, bqkv, q, k, v);

    if (Nc >= 128) {
        int lgNc = __builtin_ctz((unsigned)Nc);
        for (int n0 = 0; n0 < NSEQ; n0 += Nc) {
            scores_gemm<<<dim3(32, Nc / 128, 32), 256, 0, stream>>>(q, k, keyg, n0, Nc);
            topk_kernel<<<dim3(32 * Nc / 4), 256, 0, stream>>>(keyg, tki, tkp, tkc, n0, lgNc);
        }
    } else {
        scores_topk<<<dim3(256, 32), 256, 0, stream>>>(q, k, tki, tkp, tkc);
    }

    prop<<<dim3(NROWS / 4), 256, 0, stream>>>(v,  vA, res, araw, tki, tkp, tkc, 1);
    prop<<<dim3(NROWS / 4), 256, 0, stream>>>(vA, v,  res, araw, tki, tkp, tkc, 2);
    prop<<<dim3(NROWS / 4), 256, 0, stream>>>(v,  vA, res, araw, tki, tkp, tkc, 3);
    out_gemm<<<dim3(16, 64), 256, 0, stream>>>(res, Wout, bout, out);
}